// Round 6
// baseline (174.156 us; speedup 1.0000x reference)
//
#include <hip/hip_runtime.h>
#include <math.h>

// GPT attention block: B=8, T=1024, E=768, H=12, D=64. fp32 in/out.
// Round 16: both GEMMs -> one 128x96-tile 2-phase counted-vmcnt kernel,
// 256 threads (4 waves, 2x2), 56KB LDS double-buffer = 2 blocks/CU with
// 2x the independent barrier domains of R15's 512-thread blocks (m97's
// cross-block latency-hiding mechanism). QKV: 64x24 = 1536 blocks = 6 exact
// rounds. proj: 64x8 = 512 blocks = 2 exact rounds (replaces the old
// __syncthreads-drain gemm). Stage = 7 global_load_lds/thread; vmcnt(7).
// XCD swizzle keeps batch b on XCD b. Flash v7 / prep unchanged.

#define B_ 8
#define T_ 1024
#define E_ 768
#define H_ 12
#define D_ 64
#define E3 (3 * E_)

typedef __attribute__((ext_vector_type(8))) short bf16x8;
typedef __attribute__((ext_vector_type(4))) float f32x4;

#define SCALE 0.18033688f // 0.125 * log2(e)

__device__ __forceinline__ unsigned short f2bf(float f) {
    unsigned int u = __builtin_bit_cast(unsigned int, f);
    u += 0x7fffu + ((u >> 16) & 1u);   // RNE
    return (unsigned short)(u >> 16);
}

__device__ __forceinline__ void async_copy16(void* lds, const void* g) {
    __builtin_amdgcn_global_load_lds(
        (const __attribute__((address_space(1))) void*)g,
        (__attribute__((address_space(3))) void*)lds, 16, 0, 0);
}

// ---------------- fused prep: x->bf16, w_attn^T, w_proj^T ----------------
#define NCVT 6144                 // (8192*768/4)/256
#define NTA  (72 * 24)            // (E3/32) x (E_/32)
#define NTP  (24 * 24)            // (E_/32) x (E_/32)

__device__ __forceinline__ void transpose_tile(
    const float* __restrict__ W, unsigned short* __restrict__ Wt,
    int K, int N, int gx, int gy, unsigned short (*tile)[33])
{
    const int n0 = gx * 32, k0 = gy * 32;
    const int tx = threadIdx.x & 31, ty = threadIdx.x >> 5;
    #pragma unroll
    for (int i = 0; i < 4; ++i)
        tile[ty + i * 8][tx] = f2bf(W[(size_t)(k0 + ty + i * 8) * N + n0 + tx]);
    __syncthreads();
    #pragma unroll
    for (int i = 0; i < 4; ++i)
        Wt[(size_t)(n0 + ty + i * 8) * K + k0 + tx] = tile[tx][ty + i * 8];
}

__global__ __launch_bounds__(256) void prep_kernel(
    const float* __restrict__ x, unsigned short* __restrict__ x_bf,
    const float* __restrict__ w_attn, unsigned short* __restrict__ wat,
    const float* __restrict__ w_proj, unsigned short* __restrict__ wpt)
{
    __shared__ unsigned short tile[32][33];
    const int bid = blockIdx.x;
    if (bid < NCVT) {
        const int i = bid * 256 + threadIdx.x;
        float4 f = ((const float4*)x)[i];
        ushort4 o;
        o.x = f2bf(f.x); o.y = f2bf(f.y); o.z = f2bf(f.z); o.w = f2bf(f.w);
        ((ushort4*)x_bf)[i] = o;
    } else if (bid < NCVT + NTA) {
        const int t = bid - NCVT;
        transpose_tile(w_attn, wat, E_, E3, t % 72, t / 72, tile);
    } else {
        const int t = bid - NCVT - NTA;
        transpose_tile(w_proj, wpt, E_, E_, t % 24, t / 24, tile);
    }
}

// ---------------- 128x96-tile 2-phase GEMM (QKV and proj) ----------------
// A [8192,768] bf16; B = Wt [N_,768] bf16 (N-major, K contiguous).
// 256 threads = 4 waves (wm = w>>1, wn = w&1). Per-wave rows wm*16 + m*32
// (m=0..3), cols wn*16 + n*32 (n=0..2). acc[4][3] = 48 regs.
// LDS: [A0 16KB][A1 16KB][B0 12KB][B1 12KB] = 56KB -> 2 blocks/CU.
// Per K-tile: stage 7 ops (A 4 + B 3) of tile t+1 -> other buf; vmcnt(7);
// barrier; 14 ds_read_b128; 24 MFMA; barrier.
// MODE 1 (N_=2304): bx<8 Q (scaled), 8..15 K, >=16 V -> vt transpose.
// MODE 0 (N_=768):  fp32 out + bias.

template <typename OutT, int MODE, int N_>
__global__ __launch_bounds__(256, 2) void gemm_2ph(
    const unsigned short* __restrict__ A,
    const unsigned short* __restrict__ Wt,
    const float* __restrict__ bias,
    OutT* __restrict__ C,
    unsigned short* __restrict__ vt)
{
    constexpr int K = 768;
    constexpr int NKT = 12;                 // K / 64
    constexpr int NBX = N_ / 96;
    constexpr int QBX = 768 / 96;           // 8
    constexpr int VBX = 1536 / 96;          // 16

    extern __shared__ unsigned short lds[];

    const int tid  = threadIdx.x;
    const int lane = tid & 63;
    const int w    = tid >> 6;          // 0..3
    const int wm   = w >> 1;            // 0..1
    const int wn   = w & 1;             // 0..1
    const int n16  = lane & 15;
    const int quad = lane >> 4;

    // XCD swizzle: 8 XCDs x (8*NBX) contiguous works; batch b stays on XCD b.
    const int lin = blockIdx.x;
    const int s   = lin >> 3;
    const int by  = (lin & 7) * 8 + s / NBX;
    const int bx  = s % NBX;
    const int bm = by * 128, bn = bx * 96;

    const unsigned short* Asrc = A  + (size_t)bm * K;
    const unsigned short* Bsrc = Wt + (size_t)bn * K;

    auto stage = [&](int bi, int kt) {
        unsigned short* ab = lds + (bi ? 8192 : 0);
        unsigned short* bb = lds + 16384 + (bi ? 6144 : 0);
        #pragma unroll
        for (int i = 0; i < 4; ++i) {
            const int li = i * 256 + tid;        // 0..1023
            const int row = li >> 3;             // 0..127
            const int sl  = li & 7;
            async_copy16(&ab[li * 8],
                         Asrc + (size_t)row * K + ((sl ^ (row & 7)) * 8) + kt * 64);
        }
        #pragma unroll
        for (int i = 0; i < 3; ++i) {
            const int li = i * 256 + tid;        // 0..767
            const int row = li >> 3;             // 0..95
            const int sl  = li & 7;
            async_copy16(&bb[li * 8],
                         Bsrc + (size_t)row * K + ((sl ^ (row & 7)) * 8) + kt * 64);
        }
    };

    f32x4 acc[4][3] = {};

#define BARR  __builtin_amdgcn_s_barrier()
#define VM7   asm volatile("s_waitcnt vmcnt(7)" ::: "memory")
#define VM0   asm volatile("s_waitcnt vmcnt(0)" ::: "memory")
#define PRI1  __builtin_amdgcn_s_setprio(1)
#define PRI0  __builtin_amdgcn_s_setprio(0)

    stage(0, 0);                        // prologue: tile 0 -> buf0 (7 ops)

    #pragma unroll 1
    for (int u = 0; u < NKT; ++u) {
        const int bi = u & 1;
        const unsigned short* ab = lds + (bi ? 8192 : 0);
        const unsigned short* bb = lds + 16384 + (bi ? 6144 : 0);
        if (u < NKT - 1) {
            stage(bi ^ 1, u + 1);       // 7 ops -> other buffer
            VM7;                        // tile u's 7 landed; u+1's 7 in flight
        } else {
            VM0;
        }
        BARR;

        #pragma unroll
        for (int kc = 0; kc < 2; ++kc) {
            bf16x8 af[4], bf[3];
            #pragma unroll
            for (int m = 0; m < 4; ++m) {
                const int r = wm * 16 + m * 32 + n16;
                af[m] = *(const bf16x8*)&ab[r * 64 + (((kc * 4 + quad) ^ (r & 7)) * 8)];
            }
            #pragma unroll
            for (int n = 0; n < 3; ++n) {
                const int r = wn * 16 + n * 32 + n16;
                bf[n] = *(const bf16x8*)&bb[r * 64 + (((kc * 4 + quad) ^ (r & 7)) * 8)];
            }
            PRI1;
            #pragma unroll
            for (int m = 0; m < 4; ++m)
                #pragma unroll
                for (int n = 0; n < 3; ++n)
                    acc[m][n] = __builtin_amdgcn_mfma_f32_16x16x32_bf16(
                        af[m], bf[n], acc[m][n], 0, 0, 0);
            PRI0;
        }
        BARR;                           // close reads before next overwrite
    }

#undef VM7
#undef VM0

    // ---- epilogue ----
    if (MODE == 1 && bx >= VBX) {
        // V -> vt [(b*768 + ch)][1024]; ushort4 = 4 consecutive tokens
        #pragma unroll
        for (int m = 0; m < 4; ++m) {
            const int tt = bm + wm * 16 + m * 32 + quad * 4;
            const size_t bb2 = (size_t)(tt >> 10) * 768;
            const int tin = tt & 1023;
            #pragma unroll
            for (int n = 0; n < 3; ++n) {
                const int col = bn + wn * 16 + n * 32 + n16;
                const int ch = col - 1536;
                const float bv = bias[col];
                ushort4 o4;
                o4.x = f2bf(acc[m][n][0] + bv);
                o4.y = f2bf(acc[m][n][1] + bv);
                o4.z = f2bf(acc[m][n][2] + bv);
                o4.w = f2bf(acc[m][n][3] + bv);
                *(ushort4*)&vt[(bb2 + ch) * 1024 + tin] = o4;
            }
        }
        return;
    }

    const bool scale_q = (MODE == 1) && (bx < QBX);
    #pragma unroll
    for (int m = 0; m < 4; ++m) {
        #pragma unroll
        for (int r = 0; r < 4; ++r) {
            const size_t rowoff = (size_t)(bm + wm * 16 + m * 32 + quad * 4 + r) * N_;
            #pragma unroll
            for (int n = 0; n < 3; ++n) {
                const int col = bn + wn * 16 + n * 32 + n16;
                float v = acc[m][n][r] + bias[col];
                if (scale_q) v *= SCALE;
                if constexpr (sizeof(OutT) == 2) C[rowoff + col] = (OutT)f2bf(v);
                else                             C[rowoff + col] = (OutT)v;
            }
        }
    }
}

// ---------------- Flash attention v7 (unchanged): pipelined LDS staging, no Ps ----------------
#define BKEY 128

__global__ __launch_bounds__(256, 3) void flash_attn_kernel(
    const unsigned short* __restrict__ qkv,
    const unsigned short* __restrict__ vt,   // [(b*H+h)*64+d][1024] bf16
    unsigned short* __restrict__ out)
{
    __shared__ __align__(16) unsigned short Ks[2][BKEY * 64];   // double-buffered K
    __shared__ __align__(16) unsigned short Vts[64 * BKEY];     // single-buffered V^T

    const int tid = threadIdx.x;
    const int idx = blockIdx.x;
    const int xcd = idx & 7;
    const int j   = idx >> 3;           // 0..95
    const int head = xcd * 12 + (j % 12);
    const int p    = j / 12;            // 0..7
    const int h = head % H_;
    const int b = head / H_;

    const int lane = tid & 63;
    const int w    = tid >> 6;
    const int n16  = lane & 15;
    const int quad = lane >> 4;

    const size_t base = (size_t)b * T_ * E3;
    const unsigned short* qbase = qkv + base + h * D_;          // pre-scaled q
    const unsigned short* kbase = qkv + base + E_ + h * D_;
    const unsigned short* vtb   = vt + (size_t)(b * H_ + h) * 64 * 1024;

    const int lrow = lane >> 3;
    const int lcol = ((lane & 7) ^ lrow) * 8;
    const int vr4 = lane >> 4;
    const int vc  = lane & 15;

    const int qtA = p, qtB = 15 - p;
    const int nIterA = (qtA + 2) >> 1;
    const int nIterB = (qtB + 2) >> 1;
    const int wqA = qtA * 64 + w * 16;
    const int wqB = qtB * 64 + w * 16;

    const unsigned short* qrpA = qbase + (size_t)(wqA + n16) * E3 + quad * 8;
    bf16x8 qfA0 = *(const bf16x8*)qrpA;
    bf16x8 qfA1 = *(const bf16x8*)(qrpA + 32);
    const unsigned short* qrpB = qbase + (size_t)(wqB + n16) * E3 + quad * 8;
    bf16x8 qfB0 = *(const bf16x8*)qrpB;
    bf16x8 qfB1 = *(const bf16x8*)(qrpB + 32);

    f32x4 oA[4] = {}, oB[4] = {};
    float lsA = 0.f, lsB = 0.f;

    const int sLo = n16 + 32 * (quad & 1);
    const int sHi = sLo + 16;
    const bool hiSel = quad >= 2;

    auto stageK = [&](int t) {                 // K tile t -> Ks[t&1] (4 loads)
        unsigned short* dst = Ks[t & 1];
        const int k0 = t * BKEY;
        #pragma unroll
        for (int i = 0; i < 4; ++i) {
            const int c = w * 4 + i;
            const int row = c * 8 + lrow;
            async_copy16(&dst[c * 512], kbase + (size_t)(k0 + row) * E3 + lcol);
        }
    };
    auto stageV = [&](int t) {                 // V tile t -> Vts (4 loads)
        const int k0 = t * BKEY;
        #pragma unroll
        for (int i = 0; i < 4; ++i) {
            const int jj = w * 4 + i;
            const int row = 4 * jj + vr4;
            async_copy16(&Vts[4 * jj * BKEY],
                         vtb + (size_t)row * 1024 + k0 + ((vc ^ (row & 15)) * 8));
        }
    };

    auto phase = [&](bf16x8 qf0, bf16x8 qf1, f32x4* o, float& lsum,
                     int wave_q_min, int k0, const unsigned short* Kb,
                     bool doMid, bool notLast) {
        int knt_lim = ((wave_q_min + 15 - k0) >> 4) + 1;
        if (knt_lim > 8) knt_lim = 8;
        const int ks_lim = (knt_lim + 1) >> 1;
        const int nkp = ks_lim * 2;
        int Ab2 = wave_q_min - k0 - 15;
        int kfull = Ab2 < 0 ? 0 : (Ab2 >> 4) + 1;
        if (kfull > 8) kfull = 8;

        const int qcol = wave_q_min + n16;           // this lane's q row

        f32x4 s[8];
        #pragma unroll
        for (int knt = 0; knt < 8; ++knt) {
            if (knt < knt_lim) {
                const int r = knt * 16 + n16;
                bf16x8 kf0 = *(const bf16x8*)&Kb[r * 64 + ((0 + quad) ^ (r & 7)) * 8];
                bf16x8 kf1 = *(const bf16x8*)&Kb[r * 64 + ((4 + quad) ^ (r & 7)) * 8];
                f32x4 acc = {0.f, 0.f, 0.f, 0.f};
                acc = __builtin_amdgcn_mfma_f32_16x16x32_bf16(kf0, qf0, acc, 0, 0, 0);
                acc = __builtin_amdgcn_mfma_f32_16x16x32_bf16(kf1, qf1, acc, 0, 0, 0);
                s[knt] = acc;
            }
        }
        #pragma unroll
        for (int knt = 0; knt < 8; ++knt) {
            if (knt >= kfull && knt < nkp) {
                const int krow = k0 + knt * 16 + quad * 4;
                #pragma unroll
                for (int r = 0; r < 4; ++r) {
                    float v = (knt < knt_lim) ? s[knt][r] : -1e30f;
                    if (krow + r > qcol) v = -1e30f;
                    s[knt][r] = v;
                }
            }
        }

        unsigned int e0[8], e1[8];
        #pragma unroll
        for (int knt = 0; knt < 8; ++knt) {
            if (knt < nkp) {
                float pv0 = __builtin_amdgcn_exp2f(s[knt][0]);
                float pv1 = __builtin_amdgcn_exp2f(s[knt][1]);
                float pv2 = __builtin_amdgcn_exp2f(s[knt][2]);
                float pv3 = __builtin_amdgcn_exp2f(s[knt][3]);
                lsum += (pv0 + pv1) + (pv2 + pv3);
                unsigned int u0 = __builtin_bit_cast(unsigned int, pv0);
                unsigned int u1 = __builtin_bit_cast(unsigned int, pv1);
                unsigned int u2 = __builtin_bit_cast(unsigned int, pv2);
                unsigned int u3 = __builtin_bit_cast(unsigned int, pv3);
                e0[knt] = ((u0 + 0x8000u) >> 16) | ((u1 + 0x8000u) & 0xffff0000u);
                e1[knt] = ((u2 + 0x8000u) >> 16) | ((u3 + 0x8000u) & 0xffff0000u);
            }
        }

        if (doMid) {
            if (notLast) asm volatile("s_waitcnt vmcnt(4)" ::: "memory");
            else         asm volatile("s_waitcnt vmcnt(0)" ::: "memory");
            __builtin_amdgcn_s_barrier();
        }

        #pragma unroll
        for (int ks = 0; ks < 4; ++ks) {
            if (ks < ks_lim) {
                const int kA = 2 * ks, kB = 2 * ks + 1;
                unsigned int a0 = (unsigned)__shfl((int)e0[kA], sLo);
                unsigned int a1 = (unsigned)__shfl((int)e1[kA], sLo);
                unsigned int a2 = (unsigned)__shfl((int)e0[kA], sHi);
                unsigned int a3 = (unsigned)__shfl((int)e1[kA], sHi);
                unsigned int b0 = (unsigned)__shfl((int)e0[kB], sLo);
                unsigned int b1 = (unsigned)__shfl((int)e1[kB], sLo);
                unsigned int b2 = (unsigned)__shfl((int)e0[kB], sHi);
                unsigned int b3 = (unsigned)__shfl((int)e1[kB], sHi);
                uint4 pu;
                pu.x = hiSel ? b0 : a0;
                pu.y = hiSel ? b1 : a1;
                pu.z = hiSel ? b2 : a2;
                pu.w = hiSel ? b3 : a3;
                bf16x8 pf = __builtin_bit_cast(bf16x8, pu);
                #pragma unroll
                for (int dt = 0; dt < 4; ++dt) {
                    const int row = dt * 16 + n16;
                    bf16x8 vf = *(const bf16x8*)&Vts[row * BKEY +
                                    (((ks * 4 + quad) ^ n16) * 8)];
                    o[dt] = __builtin_amdgcn_mfma_f32_16x16x32_bf16(pf, vf, o[dt], 0, 0, 0);
                }
            }
        }
    };

    stageK(0);
    asm volatile("s_waitcnt vmcnt(0)" ::: "memory");
    __builtin_amdgcn_s_barrier();

    for (int it = 0; it < nIterB; ++it) {
        const int k0 = it * BKEY;
        const bool notLast = (it + 1 < nIterB);

        stageV(it);
        if (notLast) stageK(it + 1);
        const unsigned short* Kb = Ks[it & 1];

        phase(qfB0, qfB1, oB, lsB, wqB, k0, Kb, true,  notLast);
        if (it < nIterA)
            phase(qfA0, qfA1, oA, lsA, wqA, k0, Kb, false, notLast);

        asm volatile("s_waitcnt vmcnt(0)" ::: "memory");
        __builtin_amdgcn_s_barrier();
    }

    lsA += __shfl_xor(lsA, 16); lsA += __shfl_xor(lsA, 32);
    lsB += __shfl_xor(lsB, 16); lsB += __shfl_xor(lsB, 32);

    #pragma unroll
    for (int r = 0; r < 4; ++r) {
        const float invA = 1.f / __shfl(lsA, quad * 4 + r);
        unsigned short* orowA = out + ((size_t)b * T_ + wqA + quad * 4 + r) * E_ + h * D_;
        #pragma unroll
        for (int dt = 0; dt < 4; ++dt)
            orowA[dt * 16 + n16] = f2bf(oA[dt][r] * invA);
        const float invB = 1.f / __shfl(lsB, quad * 4 + r);
        unsigned short* orowB = out + ((size_t)b * T_ + wqB + quad * 4 + r) * E_ + h * D_;
        #pragma unroll
        for (int dt = 0; dt < 4; ++dt)
            orowB[dt * 16 + n16] = f2bf(oB[dt][r] * invB);
    }
}

extern "C" void kernel_launch(void* const* d_in, const int* in_sizes, int n_in,
                              void* d_out, int out_size, void* d_ws, size_t ws_size,
                              hipStream_t stream)
{
    const float* x      = (const float*)d_in[0];
    const float* w_attn = (const float*)d_in[1];
    const float* b_attn = (const float*)d_in[2];
    const float* w_proj = (const float*)d_in[3];
    const float* b_proj = (const float*)d_in[4];
    float* out = (float*)d_out;

    const int M = B_ * T_;  // 8192

    unsigned short* x_bf   = (unsigned short*)d_ws;           // [M,E]
    unsigned short* wat    = x_bf + (size_t)M * E_;           // [3E,E]
    unsigned short* wpt    = wat + (size_t)E3 * E_;           // [E,E]
    unsigned short* qkv_bf = wpt + (size_t)E_ * E_;           // [M,3E] (V region unused)
    unsigned short* att_bf = qkv_bf + (size_t)M * E3;         // [M,E]
    unsigned short* vt_bf  = att_bf + (size_t)M * E_;         // [B*H*64,1024]

    prep_kernel<<<NCVT + NTA + NTP, 256, 0, stream>>>(x, x_bf, w_attn, wat, w_proj, wpt);

    gemm_2ph<unsigned short, 1, E3><<<dim3(1536), dim3(256), 57344, stream>>>(
        x_bf, wat, b_attn, qkv_bf, vt_bf);

    flash_attn_kernel<<<B_ * H_ * 8, 256, 0, stream>>>(qkv_bf, vt_bf, att_bf);

    gemm_2ph<float, 0, E_><<<dim3(512), dim3(256), 57344, stream>>>(
        att_bf, wpt, b_proj, out, nullptr);
}

// Round 8
// 172.759 us; speedup vs baseline: 1.0081x; 1.0081x over previous
//
#include <hip/hip_runtime.h>
#include <math.h>

// GPT attention block: B=8, T=1024, E=768, H=12, D=64. fp32 in/out.
// Round 18 (= R17 resubmit; infra failure, kernel audit clean): QKV ->
// 256x288 tile, grid 32x8 = exactly 256 blocks (1/CU, zero quantization;
// 2304=9*256 so the 9 is absorbed into the tile). 512 threads, 8 waves 4x2,
// per-wave 64x144 (acc[4][9]) -> ds_read_b128 density 0.00282/out-elem
// (R15: 0.00456), attacking the measured LDS-read bound. 6 phases/K-tile,
// order (0,0)(1,0)(1,1)(0,1)(0,2)(1,2); A-halves in registers across phases,
// one B-third live. Double-buffered LDS 136KB. Staging P1:A0 P2:A1 P3:Bg1
// P4:Bg2 P5:Bg3 (4 real + 4 idempotent pad ops, uniform per-wave counts);
// counted waits vmcnt(5)@P2, vmcnt(8)@P4, vmcnt(3)@P6 - never 0 in loop.
// Proj = R5's gemm_mfma_kernel. Flash v7 / prep unchanged.

#define B_ 8
#define T_ 1024
#define E_ 768
#define H_ 12
#define D_ 64
#define E3 (3 * E_)

typedef __attribute__((ext_vector_type(8))) short bf16x8;
typedef __attribute__((ext_vector_type(4))) float f32x4;

#define SCALE 0.18033688f // 0.125 * log2(e)

__device__ __forceinline__ unsigned short f2bf(float f) {
    unsigned int u = __builtin_bit_cast(unsigned int, f);
    u += 0x7fffu + ((u >> 16) & 1u);   // RNE
    return (unsigned short)(u >> 16);
}

__device__ __forceinline__ void async_copy16(void* lds, const void* g) {
    __builtin_amdgcn_global_load_lds(
        (const __attribute__((address_space(1))) void*)g,
        (__attribute__((address_space(3))) void*)lds, 16, 0, 0);
}

// ---------------- fused prep: x->bf16, w_attn^T, w_proj^T ----------------
#define NCVT 6144                 // (8192*768/4)/256
#define NTA  (72 * 24)            // (E3/32) x (E_/32)
#define NTP  (24 * 24)            // (E_/32) x (E_/32)

__device__ __forceinline__ void transpose_tile(
    const float* __restrict__ W, unsigned short* __restrict__ Wt,
    int K, int N, int gx, int gy, unsigned short (*tile)[33])
{
    const int n0 = gx * 32, k0 = gy * 32;
    const int tx = threadIdx.x & 31, ty = threadIdx.x >> 5;
    #pragma unroll
    for (int i = 0; i < 4; ++i)
        tile[ty + i * 8][tx] = f2bf(W[(size_t)(k0 + ty + i * 8) * N + n0 + tx]);
    __syncthreads();
    #pragma unroll
    for (int i = 0; i < 4; ++i)
        Wt[(size_t)(n0 + ty + i * 8) * K + k0 + tx] = tile[tx][ty + i * 8];
}

__global__ __launch_bounds__(256) void prep_kernel(
    const float* __restrict__ x, unsigned short* __restrict__ x_bf,
    const float* __restrict__ w_attn, unsigned short* __restrict__ wat,
    const float* __restrict__ w_proj, unsigned short* __restrict__ wpt)
{
    __shared__ unsigned short tile[32][33];
    const int bid = blockIdx.x;
    if (bid < NCVT) {
        const int i = bid * 256 + threadIdx.x;
        float4 f = ((const float4*)x)[i];
        ushort4 o;
        o.x = f2bf(f.x); o.y = f2bf(f.y); o.z = f2bf(f.z); o.w = f2bf(f.w);
        ((ushort4*)x_bf)[i] = o;
    } else if (bid < NCVT + NTA) {
        const int t = bid - NCVT;
        transpose_tile(w_attn, wat, E_, E3, t % 72, t / 72, tile);
    } else {
        const int t = bid - NCVT - NTA;
        transpose_tile(w_proj, wpt, E_, E_, t % 24, t / 24, tile);
    }
}

// ---------------- QKV GEMM: 256x288, 256 blocks, 6-phase ----------------
__global__ __launch_bounds__(512, 2) void gemm_qkv_288(
    const unsigned short* __restrict__ A,   // [8192,768] bf16
    const unsigned short* __restrict__ Wt,  // [2304,768] bf16
    const float* __restrict__ bias,
    unsigned short* __restrict__ C,         // [8192,2304] bf16 (Q,K regions)
    unsigned short* __restrict__ vt)        // [B*H*64,1024] bf16
{
    constexpr int K = 768;
    constexpr int NKT = 12;                 // K / 64

    // LDS (ushort units): Ab0 @0 (16384), Ab1 @16384, Bb0 @32768 (18432),
    // Bb1 @51200. Total 69632 us = 136 KiB.
    extern __shared__ unsigned short lds[];

    const int tid  = threadIdx.x;
    const int lane = tid & 63;
    const int w    = tid >> 6;          // 0..7
    const int wm   = w & 3;             // 0..3 rows
    const int wn   = w >> 2;            // 0..1 cols
    const int n16  = lane & 15;
    const int quad = lane >> 4;
    const int l7   = lane & 7;
    const int lrow = lane >> 3;
    const int lcol = (l7 ^ lrow) * 8;   // pre-swizzled source column group

    // 256 blocks: xcd = lin&7 -> batch xcd rows (L2 affinity), bx 0..7.
    const int lin = blockIdx.x;
    const int j   = lin >> 3;           // 0..31
    const int by  = (lin & 7) * 4 + (j & 3);
    const int bx  = j >> 2;             // 0..7
    const int bm = by * 256, bn = bx * 288;

    const unsigned short* Asrc = A  + (size_t)bm * K;
    const unsigned short* Bsrc = Wt + (size_t)bn * K;

    auto stA0 = [&](int bi, int kt) {   // A rows [0,128): 16 wave-ops, 2/wave
        unsigned short* ab = lds + (bi ? 16384 : 0);
        #pragma unroll
        for (int s = 0; s < 2; ++s) {
            const int c = w * 2 + s;
            async_copy16(&ab[c * 512], Asrc + (size_t)(c * 8 + lrow) * K + kt * 64 + lcol);
        }
    };
    auto stA1 = [&](int bi, int kt) {   // A rows [128,256)
        unsigned short* ab = lds + (bi ? 16384 : 0);
        #pragma unroll
        for (int s = 0; s < 2; ++s) {
            const int c = 16 + w * 2 + s;
            async_copy16(&ab[c * 512], Asrc + (size_t)(c * 8 + lrow) * K + kt * 64 + lcol);
        }
    };
    auto stB01 = [&](int g, int bi, int kt) {  // B rows [g*128,(g+1)*128)
        unsigned short* bb = lds + 32768 + (bi ? 18432 : 0);
        #pragma unroll
        for (int s = 0; s < 2; ++s) {
            const int c = g * 16 + w * 2 + s;
            async_copy16(&bb[c * 512], Bsrc + (size_t)(c * 8 + lrow) * K + kt * 64 + lcol);
        }
    };
    auto stB2 = [&](int bi, int kt) {   // B rows [256,288) + idempotent pad
        unsigned short* bb = lds + 32768 + (bi ? 18432 : 0);
        const int c = (w < 4) ? (32 + w) : (w - 4);
        async_copy16(&bb[c * 512], Bsrc + (size_t)(c * 8 + lrow) * K + kt * 64 + lcol);
    };

    bf16x8 a0f[4], a1f[4], bfr[6];
    f32x4 acc[4][9] = {};

#define BARR  __builtin_amdgcn_s_barrier()
#define LGKM0 asm volatile("s_waitcnt lgkmcnt(0)" ::: "memory")
#define VM3   asm volatile("s_waitcnt vmcnt(3)" ::: "memory")
#define VM5   asm volatile("s_waitcnt vmcnt(5)" ::: "memory")
#define VM8   asm volatile("s_waitcnt vmcnt(8)" ::: "memory")
#define PRI1  __builtin_amdgcn_s_setprio(1)
#define PRI0  __builtin_amdgcn_s_setprio(0)

// A-half QM frags (4 ds_read_b128)
#define LDA_(dst, QM) { \
    _Pragma("unroll") \
    for (int ml = 0; ml < 2; ++ml) { \
        const int r = wm * 16 + ((QM) * 2 + ml) * 64 + n16; \
        const unsigned short* rp = ab + r * 64; \
        dst[ml * 2 + 0] = *(const bf16x8*)&rp[((0 + quad) ^ (r & 7)) * 8]; \
        dst[ml * 2 + 1] = *(const bf16x8*)&rp[((4 + quad) ^ (r & 7)) * 8]; \
    } }
// B-third QT frags (6 ds_read_b128)
#define LDB_(QT) { \
    _Pragma("unroll") \
    for (int nl = 0; nl < 3; ++nl) { \
        const int r = wn * 16 + ((QT) * 3 + nl) * 32 + n16; \
        const unsigned short* rp = bb + r * 64; \
        bfr[nl * 2 + 0] = *(const bf16x8*)&rp[((0 + quad) ^ (r & 7)) * 8]; \
        bfr[nl * 2 + 1] = *(const bf16x8*)&rp[((4 + quad) ^ (r & 7)) * 8]; \
    } }
// 12 MFMA: quadrant (QM, QT)
#define MM_(QM, QT, AF) { \
    _Pragma("unroll") \
    for (int ml = 0; ml < 2; ++ml) \
    _Pragma("unroll") \
    for (int nl = 0; nl < 3; ++nl) \
    _Pragma("unroll") \
    for (int kk = 0; kk < 2; ++kk) \
        acc[(QM) * 2 + ml][(QT) * 3 + nl] = __builtin_amdgcn_mfma_f32_16x16x32_bf16( \
            AF[ml * 2 + kk], bfr[nl * 2 + kk], acc[(QM) * 2 + ml][(QT) * 3 + nl], 0, 0, 0); }

    // prologue: tile 0 -> buf0, full drain once
    stA0(0, 0); stA1(0, 0); stB01(0, 0, 0); stB01(1, 0, 0); stB2(0, 0);
    asm volatile("s_waitcnt vmcnt(0)" ::: "memory");
    BARR;

    #pragma unroll 1
    for (int t = 0; t < NKT; ++t) {
        const int bi = t & 1;
        const unsigned short* ab = lds + (bi ? 16384 : 0);
        const unsigned short* bb = lds + 32768 + (bi ? 18432 : 0);
        const bool st = (t < NKT - 1);

        // P1 (0,0): load A0,B0
        LDA_(a0f, 0); LDB_(0);
        if (st) stA0(bi ^ 1, t + 1);
        BARR; LGKM0; PRI1; MM_(0, 0, a0f); PRI0; BARR;
        // P2 (1,0): load A1; B0 reused -> dead after
        LDA_(a1f, 1);
        if (st) stA1(bi ^ 1, t + 1);
        BARR; LGKM0; PRI1; MM_(1, 0, a1f); PRI0; VM5; BARR;
        // P3 (1,1): load B1
        LDB_(1);
        if (st) stB01(0, bi ^ 1, t + 1);
        BARR; LGKM0; PRI1; MM_(1, 1, a1f); PRI0; BARR;
        // P4 (0,1): reuse a0f,B1 (no loads)
        if (st) stB01(1, bi ^ 1, t + 1);
        BARR; LGKM0; PRI1; MM_(0, 1, a0f); PRI0; VM8; BARR;
        // P5 (0,2): load B2
        LDB_(2);
        if (st) stB2(bi ^ 1, t + 1);
        BARR; LGKM0; PRI1; MM_(0, 2, a0f); PRI0; BARR;
        // P6 (1,2): reuse a1f,B2
        BARR; LGKM0; PRI1; MM_(1, 2, a1f); PRI0; VM3; BARR;
    }

#undef LDA_
#undef LDB_
#undef MM_
#undef VM3
#undef VM5
#undef VM8

    // ---- epilogue: per-nt region (Q scaled / K / V -> vt transpose) ----
    #pragma unroll
    for (int mt = 0; mt < 4; ++mt) {
        const int rowb = bm + wm * 16 + mt * 64 + quad * 4;
        #pragma unroll
        for (int nt = 0; nt < 9; ++nt) {
            const int cb = bn + wn * 16 + nt * 32;   // 16-aligned -> region uniform
            const int col = cb + n16;
            const float bv = bias[col];
            if (cb < 1536) {
                const float sc = (cb < 768) ? SCALE : 1.0f;
                #pragma unroll
                for (int r = 0; r < 4; ++r)
                    C[(size_t)(rowb + r) * E3 + col] = f2bf((acc[mt][nt][r] + bv) * sc);
            } else {
                const size_t bb2 = (size_t)(rowb >> 10) * 768;
                const int tin = rowb & 1023;
                const int ch = col - 1536;
                ushort4 o4;
                o4.x = f2bf(acc[mt][nt][0] + bv);
                o4.y = f2bf(acc[mt][nt][1] + bv);
                o4.z = f2bf(acc[mt][nt][2] + bv);
                o4.w = f2bf(acc[mt][nt][3] + bv);
                *(ushort4*)&vt[(bb2 + ch) * 1024 + tin] = o4;
            }
        }
    }
}

// ---------------- bf16 MFMA GEMM (proj, as in R5) ----------------
template <typename OutT, int MODE, int BM, int BN, int WR, int WC>
__global__ __launch_bounds__(256) void gemm_mfma_kernel(
    const unsigned short* __restrict__ A,   // [M,K] bf16
    const unsigned short* __restrict__ Wt,  // [N,K] bf16
    const float* __restrict__ bias,
    OutT* __restrict__ C,
    unsigned short* __restrict__ vt,
    int M, int N, int K)
{
    constexpr int MT = BM / WR / 16;
    constexpr int NT = BN / WC / 16;
    constexpr int CA = BM / 32;
    constexpr int CB = BN / 32;
    constexpr int QBX = 768 / BN;
    constexpr int VBX = 1536 / BN;

    __shared__ unsigned short Abuf[BM * 64];
    __shared__ unsigned short Bbuf[BN * 64];

    const int tid = threadIdx.x;
    const int lane = tid & 63;
    const int w = tid >> 6;
    const int n16 = lane & 15;
    const int quad = lane >> 4;

    const int nbx = gridDim.x;
    const int lin = blockIdx.y * nbx + blockIdx.x;
    const int band_sz = 8 * nbx;
    const int band = lin / band_sz;
    const int rr = lin % band_sz;
    const int bm = (band * 8 + (rr & 7)) * BM;
    const int bx = rr >> 3;
    const int bn = bx * BN;

    const int wmbase = (w / WC) * (BM / WR);
    const int wnbase = (w % WC) * (BN / WC);

    const int lrow = lane >> 3;
    const int lcol = ((lane & 7) ^ lrow) * 8;

    f32x4 acc[MT][NT] = {};

    for (int k0 = 0; k0 < K; k0 += 64) {
        __syncthreads();
        #pragma unroll
        for (int i = 0; i < CA; ++i) {
            const int c = w * CA + i;
            const int row = c * 8 + lrow;
            async_copy16(&Abuf[c * 512], A + (size_t)(bm + row) * K + k0 + lcol);
        }
        #pragma unroll
        for (int i = 0; i < CB; ++i) {
            const int c = w * CB + i;
            const int row = c * 8 + lrow;
            async_copy16(&Bbuf[c * 512], Wt + (size_t)(bn + row) * K + k0 + lcol);
        }
        __syncthreads();

        #pragma unroll
        for (int kc = 0; kc < 2; ++kc) {
            bf16x8 af[MT], bf[NT];
            #pragma unroll
            for (int mt = 0; mt < MT; ++mt) {
                const int r = wmbase + mt * 16 + n16;
                af[mt] = *(const bf16x8*)&Abuf[r * 64 + ((kc * 4 + quad) ^ (r & 7)) * 8];
            }
            #pragma unroll
            for (int nt = 0; nt < NT; ++nt) {
                const int r = wnbase + nt * 16 + n16;
                bf[nt] = *(const bf16x8*)&Bbuf[r * 64 + ((kc * 4 + quad) ^ (r & 7)) * 8];
            }
            #pragma unroll
            for (int mt = 0; mt < MT; ++mt)
                #pragma unroll
                for (int nt = 0; nt < NT; ++nt)
                    acc[mt][nt] = __builtin_amdgcn_mfma_f32_16x16x32_bf16(
                        af[mt], bf[nt], acc[mt][nt], 0, 0, 0);
        }
    }

    if (MODE == 1 && bx >= VBX) {
        #pragma unroll
        for (int mt = 0; mt < MT; ++mt) {
            const int tt = bm + wmbase + mt * 16 + quad * 4;
            const size_t bb = (size_t)(tt >> 10) * 768;
            const int tin = tt & 1023;
            #pragma unroll
            for (int nt = 0; nt < NT; ++nt) {
                const int col = bn + wnbase + nt * 16 + n16;
                const int ch = col - 1536;
                const float bv = bias[col];
                ushort4 o4;
                o4.x = f2bf(acc[mt][nt][0] + bv);
                o4.y = f2bf(acc[mt][nt][1] + bv);
                o4.z = f2bf(acc[mt][nt][2] + bv);
                o4.w = f2bf(acc[mt][nt][3] + bv);
                *(ushort4*)&vt[(bb + ch) * 1024 + tin] = o4;
            }
        }
        return;
    }

    const bool scale_q = (MODE == 1) && (bx < QBX);
    #pragma unroll
    for (int mt = 0; mt < MT; ++mt) {
        #pragma unroll
        for (int r = 0; r < 4; ++r) {
            const size_t rowoff = (size_t)(bm + wmbase + mt * 16 + quad * 4 + r) * N;
            #pragma unroll
            for (int nt = 0; nt < NT; ++nt) {
                const int col = bn + wnbase + nt * 16 + n16;
                float v = acc[mt][nt][r] + bias[col];
                if (scale_q) v *= SCALE;
                if constexpr (sizeof(OutT) == 2) C[rowoff + col] = (OutT)f2bf(v);
                else                             C[rowoff + col] = (OutT)v;
            }
        }
    }
}

// ---------------- Flash attention v7 (unchanged): pipelined LDS staging, no Ps ----------------
#define BKEY 128

__global__ __launch_bounds__(256, 3) void flash_attn_kernel(
    const unsigned short* __restrict__ qkv,
    const unsigned short* __restrict__ vt,   // [(b*H+h)*64+d][1024] bf16
    unsigned short* __restrict__ out)
{
    __shared__ __align__(16) unsigned short Ks[2][BKEY * 64];   // double-buffered K
    __shared__ __align__(16) unsigned short Vts[64 * BKEY];     // single-buffered V^T

    const int tid = threadIdx.x;
    const int idx = blockIdx.x;
    const int xcd = idx & 7;
    const int j   = idx >> 3;           // 0..95
    const int head = xcd * 12 + (j % 12);
    const int p    = j / 12;            // 0..7
    const int h = head % H_;
    const int b = head / H_;

    const int lane = tid & 63;
    const int w    = tid >> 6;
    const int n16  = lane & 15;
    const int quad = lane >> 4;

    const size_t base = (size_t)b * T_ * E3;
    const unsigned short* qbase = qkv + base + h * D_;          // pre-scaled q
    const unsigned short* kbase = qkv + base + E_ + h * D_;
    const unsigned short* vtb   = vt + (size_t)(b * H_ + h) * 64 * 1024;

    const int lrow = lane >> 3;
    const int lcol = ((lane & 7) ^ lrow) * 8;
    const int vr4 = lane >> 4;
    const int vc  = lane & 15;

    const int qtA = p, qtB = 15 - p;
    const int nIterA = (qtA + 2) >> 1;
    const int nIterB = (qtB + 2) >> 1;
    const int wqA = qtA * 64 + w * 16;
    const int wqB = qtB * 64 + w * 16;

    const unsigned short* qrpA = qbase + (size_t)(wqA + n16) * E3 + quad * 8;
    bf16x8 qfA0 = *(const bf16x8*)qrpA;
    bf16x8 qfA1 = *(const bf16x8*)(qrpA + 32);
    const unsigned short* qrpB = qbase + (size_t)(wqB + n16) * E3 + quad * 8;
    bf16x8 qfB0 = *(const bf16x8*)qrpB;
    bf16x8 qfB1 = *(const bf16x8*)(qrpB + 32);

    f32x4 oA[4] = {}, oB[4] = {};
    float lsA = 0.f, lsB = 0.f;

    const int sLo = n16 + 32 * (quad & 1);
    const int sHi = sLo + 16;
    const bool hiSel = quad >= 2;

    auto stageK = [&](int t) {                 // K tile t -> Ks[t&1] (4 loads)
        unsigned short* dst = Ks[t & 1];
        const int k0 = t * BKEY;
        #pragma unroll
        for (int i = 0; i < 4; ++i) {
            const int c = w * 4 + i;
            const int row = c * 8 + lrow;
            async_copy16(&dst[c * 512], kbase + (size_t)(k0 + row) * E3 + lcol);
        }
    };
    auto stageV = [&](int t) {                 // V tile t -> Vts (4 loads)
        const int k0 = t * BKEY;
        #pragma unroll
        for (int i = 0; i < 4; ++i) {
            const int jj = w * 4 + i;
            const int row = 4 * jj + vr4;
            async_copy16(&Vts[4 * jj * BKEY],
                         vtb + (size_t)row * 1024 + k0 + ((vc ^ (row & 15)) * 8));
        }
    };

    auto phase = [&](bf16x8 qf0, bf16x8 qf1, f32x4* o, float& lsum,
                     int wave_q_min, int k0, const unsigned short* Kb,
                     bool doMid, bool notLast) {
        int knt_lim = ((wave_q_min + 15 - k0) >> 4) + 1;
        if (knt_lim > 8) knt_lim = 8;
        const int ks_lim = (knt_lim + 1) >> 1;
        const int nkp = ks_lim * 2;
        int Ab2 = wave_q_min - k0 - 15;
        int kfull = Ab2 < 0 ? 0 : (Ab2 >> 4) + 1;
        if (kfull > 8) kfull = 8;

        const int qcol = wave_q_min + n16;           // this lane's q row

        f32x4 s[8];
        #pragma unroll
        for (int knt = 0; knt < 8; ++knt) {
            if (knt < knt_lim) {
                const int r = knt * 16 + n16;
                bf16x8 kf0 = *(const bf16x8*)&Kb[r * 64 + ((0 + quad) ^ (r & 7)) * 8];
                bf16x8 kf1 = *(const bf16x8*)&Kb[r * 64 + ((4 + quad) ^ (r & 7)) * 8];
                f32x4 acc = {0.f, 0.f, 0.f, 0.f};
                acc = __builtin_amdgcn_mfma_f32_16x16x32_bf16(kf0, qf0, acc, 0, 0, 0);
                acc = __builtin_amdgcn_mfma_f32_16x16x32_bf16(kf1, qf1, acc, 0, 0, 0);
                s[knt] = acc;
            }
        }
        #pragma unroll
        for (int knt = 0; knt < 8; ++knt) {
            if (knt >= kfull && knt < nkp) {
                const int krow = k0 + knt * 16 + quad * 4;
                #pragma unroll
                for (int r = 0; r < 4; ++r) {
                    float v = (knt < knt_lim) ? s[knt][r] : -1e30f;
                    if (krow + r > qcol) v = -1e30f;
                    s[knt][r] = v;
                }
            }
        }

        unsigned int e0[8], e1[8];
        #pragma unroll
        for (int knt = 0; knt < 8; ++knt) {
            if (knt < nkp) {
                float pv0 = __builtin_amdgcn_exp2f(s[knt][0]);
                float pv1 = __builtin_amdgcn_exp2f(s[knt][1]);
                float pv2 = __builtin_amdgcn_exp2f(s[knt][2]);
                float pv3 = __builtin_amdgcn_exp2f(s[knt][3]);
                lsum += (pv0 + pv1) + (pv2 + pv3);
                unsigned int u0 = __builtin_bit_cast(unsigned int, pv0);
                unsigned int u1 = __builtin_bit_cast(unsigned int, pv1);
                unsigned int u2 = __builtin_bit_cast(unsigned int, pv2);
                unsigned int u3 = __builtin_bit_cast(unsigned int, pv3);
                e0[knt] = ((u0 + 0x8000u) >> 16) | ((u1 + 0x8000u) & 0xffff0000u);
                e1[knt] = ((u2 + 0x8000u) >> 16) | ((u3 + 0x8000u) & 0xffff0000u);
            }
        }

        if (doMid) {
            if (notLast) asm volatile("s_waitcnt vmcnt(4)" ::: "memory");
            else         asm volatile("s_waitcnt vmcnt(0)" ::: "memory");
            __builtin_amdgcn_s_barrier();
        }

        #pragma unroll
        for (int ks = 0; ks < 4; ++ks) {
            if (ks < ks_lim) {
                const int kA = 2 * ks, kB = 2 * ks + 1;
                unsigned int a0 = (unsigned)__shfl((int)e0[kA], sLo);
                unsigned int a1 = (unsigned)__shfl((int)e1[kA], sLo);
                unsigned int a2 = (unsigned)__shfl((int)e0[kA], sHi);
                unsigned int a3 = (unsigned)__shfl((int)e1[kA], sHi);
                unsigned int b0 = (unsigned)__shfl((int)e0[kB], sLo);
                unsigned int b1 = (unsigned)__shfl((int)e1[kB], sLo);
                unsigned int b2 = (unsigned)__shfl((int)e0[kB], sHi);
                unsigned int b3 = (unsigned)__shfl((int)e1[kB], sHi);
                uint4 pu;
                pu.x = hiSel ? b0 : a0;
                pu.y = hiSel ? b1 : a1;
                pu.z = hiSel ? b2 : a2;
                pu.w = hiSel ? b3 : a3;
                bf16x8 pf = __builtin_bit_cast(bf16x8, pu);
                #pragma unroll
                for (int dt = 0; dt < 4; ++dt) {
                    const int row = dt * 16 + n16;
                    bf16x8 vf = *(const bf16x8*)&Vts[row * BKEY +
                                    (((ks * 4 + quad) ^ n16) * 8)];
                    o[dt] = __builtin_amdgcn_mfma_f32_16x16x32_bf16(pf, vf, o[dt], 0, 0, 0);
                }
            }
        }
    };

    stageK(0);
    asm volatile("s_waitcnt vmcnt(0)" ::: "memory");
    __builtin_amdgcn_s_barrier();

    for (int it = 0; it < nIterB; ++it) {
        const int k0 = it * BKEY;
        const bool notLast = (it + 1 < nIterB);

        stageV(it);
        if (notLast) stageK(it + 1);
        const unsigned short* Kb = Ks[it & 1];

        phase(qfB0, qfB1, oB, lsB, wqB, k0, Kb, true,  notLast);
        if (it < nIterA)
            phase(qfA0, qfA1, oA, lsA, wqA, k0, Kb, false, notLast);

        asm volatile("s_waitcnt vmcnt(0)" ::: "memory");
        __builtin_amdgcn_s_barrier();
    }

    lsA += __shfl_xor(lsA, 16); lsA += __shfl_xor(lsA, 32);
    lsB += __shfl_xor(lsB, 16); lsB += __shfl_xor(lsB, 32);

    #pragma unroll
    for (int r = 0; r < 4; ++r) {
        const float invA = 1.f / __shfl(lsA, quad * 4 + r);
        unsigned short* orowA = out + ((size_t)b * T_ + wqA + quad * 4 + r) * E_ + h * D_;
        #pragma unroll
        for (int dt = 0; dt < 4; ++dt)
            orowA[dt * 16 + n16] = f2bf(oA[dt][r] * invA);
        const float invB = 1.f / __shfl(lsB, quad * 4 + r);
        unsigned short* orowB = out + ((size_t)b * T_ + wqB + quad * 4 + r) * E_ + h * D_;
        #pragma unroll
        for (int dt = 0; dt < 4; ++dt)
            orowB[dt * 16 + n16] = f2bf(oB[dt][r] * invB);
    }
}

extern "C" void kernel_launch(void* const* d_in, const int* in_sizes, int n_in,
                              void* d_out, int out_size, void* d_ws, size_t ws_size,
                              hipStream_t stream)
{
    const float* x      = (const float*)d_in[0];
    const float* w_attn = (const float*)d_in[1];
    const float* b_attn = (const float*)d_in[2];
    const float* w_proj = (const float*)d_in[3];
    const float* b_proj = (const float*)d_in[4];
    float* out = (float*)d_out;

    const int M = B_ * T_;  // 8192

    unsigned short* x_bf   = (unsigned short*)d_ws;           // [M,E]
    unsigned short* wat    = x_bf + (size_t)M * E_;           // [3E,E]
    unsigned short* wpt    = wat + (size_t)E3 * E_;           // [E,E]
    unsigned short* qkv_bf = wpt + (size_t)E_ * E_;           // [M,3E] (V region unused)
    unsigned short* att_bf = qkv_bf + (size_t)M * E3;         // [M,E]
    unsigned short* vt_bf  = att_bf + (size_t)M * E_;         // [B*H*64,1024]

    static bool qkv_attr_set = false;
    if (!qkv_attr_set) {
        (void)hipFuncSetAttribute((const void*)gemm_qkv_288,
                                  hipFuncAttributeMaxDynamicSharedMemorySize, 139264);
        qkv_attr_set = true;
    }

    prep_kernel<<<NCVT + NTA + NTP, 256, 0, stream>>>(x, x_bf, w_attn, wat, w_proj, wpt);

    gemm_qkv_288<<<dim3(256), dim3(512), 139264, stream>>>(
        x_bf, wat, b_attn, qkv_bf, vt_bf);

    flash_attn_kernel<<<B_ * H_ * 8, 256, 0, stream>>>(qkv_bf, vt_bf, att_bf);

    gemm_mfma_kernel<float, 0, 64, 128, 2, 2>
        <<<dim3(E_ / 128, M / 64), 256, 0, stream>>>(
        att_bf, wpt, b_proj, out, nullptr, M, E_, E_);
}

// Round 9
// 170.120 us; speedup vs baseline: 1.0237x; 1.0155x over previous
//
#include <hip/hip_runtime.h>
#include <math.h>

// GPT attention block: B=8, T=1024, E=768, H=12, D=64. fp32 in/out.
// Round 19: QKV reverted to R15's measured-best 128x192 2-phase kernel
// (41.7us; R17/18's 6-phase was 43.3 — 136KB LDS meant 1 block/CU, every
// wait exposed). Proj rebuilt on the same verified 2-phase counted-vmcnt
// skeleton: 64x192 tile, grid 128x4 = 512 blocks = exactly 2/CU x 256 CUs
// (one round, zero quantization), 64KB LDS dbuf -> 2 blocks/CU co-resident,
// 8 staging ops/thread -> vmcnt(8), batch->XCD affinity.
// Flash v7 / prep unchanged.

#define B_ 8
#define T_ 1024
#define E_ 768
#define H_ 12
#define D_ 64
#define E3 (3 * E_)

typedef __attribute__((ext_vector_type(8))) short bf16x8;
typedef __attribute__((ext_vector_type(4))) float f32x4;

#define SCALE 0.18033688f // 0.125 * log2(e)

__device__ __forceinline__ unsigned short f2bf(float f) {
    unsigned int u = __builtin_bit_cast(unsigned int, f);
    u += 0x7fffu + ((u >> 16) & 1u);   // RNE
    return (unsigned short)(u >> 16);
}

__device__ __forceinline__ void async_copy16(void* lds, const void* g) {
    __builtin_amdgcn_global_load_lds(
        (const __attribute__((address_space(1))) void*)g,
        (__attribute__((address_space(3))) void*)lds, 16, 0, 0);
}

// ---------------- fused prep: x->bf16, w_attn^T, w_proj^T ----------------
#define NCVT 6144                 // (8192*768/4)/256
#define NTA  (72 * 24)            // (E3/32) x (E_/32)
#define NTP  (24 * 24)            // (E_/32) x (E_/32)

__device__ __forceinline__ void transpose_tile(
    const float* __restrict__ W, unsigned short* __restrict__ Wt,
    int K, int N, int gx, int gy, unsigned short (*tile)[33])
{
    const int n0 = gx * 32, k0 = gy * 32;
    const int tx = threadIdx.x & 31, ty = threadIdx.x >> 5;
    #pragma unroll
    for (int i = 0; i < 4; ++i)
        tile[ty + i * 8][tx] = f2bf(W[(size_t)(k0 + ty + i * 8) * N + n0 + tx]);
    __syncthreads();
    #pragma unroll
    for (int i = 0; i < 4; ++i)
        Wt[(size_t)(n0 + ty + i * 8) * K + k0 + tx] = tile[tx][ty + i * 8];
}

__global__ __launch_bounds__(256) void prep_kernel(
    const float* __restrict__ x, unsigned short* __restrict__ x_bf,
    const float* __restrict__ w_attn, unsigned short* __restrict__ wat,
    const float* __restrict__ w_proj, unsigned short* __restrict__ wpt)
{
    __shared__ unsigned short tile[32][33];
    const int bid = blockIdx.x;
    if (bid < NCVT) {
        const int i = bid * 256 + threadIdx.x;
        float4 f = ((const float4*)x)[i];
        ushort4 o;
        o.x = f2bf(f.x); o.y = f2bf(f.y); o.z = f2bf(f.z); o.w = f2bf(f.w);
        ((ushort4*)x_bf)[i] = o;
    } else if (bid < NCVT + NTA) {
        const int t = bid - NCVT;
        transpose_tile(w_attn, wat, E_, E3, t % 72, t / 72, tile);
    } else {
        const int t = bid - NCVT - NTA;
        transpose_tile(w_proj, wpt, E_, E_, t % 24, t / 24, tile);
    }
}

// ---------------- QKV GEMM: 128x192 tile, 2-phase counted-vmcnt (R15) ----------------
__global__ __launch_bounds__(512, 4) void gemm_qkv_128x192(
    const unsigned short* __restrict__ A,   // [8192,768] bf16
    const unsigned short* __restrict__ Wt,  // [2304,768] bf16
    const float* __restrict__ bias,
    unsigned short* __restrict__ C,         // [8192,2304] bf16 (Q,K regions)
    unsigned short* __restrict__ vt)        // [B*H*64,1024] bf16
{
    constexpr int K = 768;
    constexpr int N = E3;
    constexpr int NKT = 12;                 // K / 64

    // layout: [buf0 A 8192][buf1 A 8192][buf0 B 12288][buf1 B 12288] (ushorts)
    extern __shared__ unsigned short lds[];

    const int tid  = threadIdx.x;
    const int lane = tid & 63;
    const int w    = tid >> 6;          // 0..7
    const int wm   = w >> 2;            // 0..1
    const int wn   = w & 3;             // 0..3
    const int n16  = lane & 15;
    const int quad = lane >> 4;
    const int l7   = lane & 7;
    const int lrow = lane >> 3;
    const int lcol = (l7 ^ lrow) * 8;   // pre-swizzled source column group

    // XCD-chunked swizzle: 768 blocks = 8 XCDs x 96; XCD x covers rows of
    // batch x (by = 8x + s/12) -> preserves flash's b-affinity.
    const int lin  = blockIdx.x;
    const int s    = lin >> 3;
    const int by   = (lin & 7) * 8 + s / 12;
    const int bx   = s % 12;
    const int bm = by * 128, bn = bx * 192;

    const unsigned short* Asrc = A  + (size_t)(bm + lrow) * K + lcol;
    const unsigned short* Bsrc = Wt + (size_t)(bn + lrow) * K + lcol;

    auto stage = [&](int bi, int kt) {
        unsigned short* ab = lds + (bi ? 8192 : 0);
        unsigned short* bb = lds + 16384 + (bi ? 12288 : 0);
        #pragma unroll
        for (int i = 0; i < 2; ++i) {
            const int c = w * 2 + i;                  // 0..15 (8 rows each)
            async_copy16(&ab[c * 512], Asrc + (size_t)(c * 8) * K + kt * 64);
        }
        #pragma unroll
        for (int i = 0; i < 3; ++i) {
            const int c = w * 3 + i;                  // 0..23
            async_copy16(&bb[c * 512], Bsrc + (size_t)(c * 8) * K + kt * 64);
        }
    };

    f32x4 acc[4][3] = {};

#define BARR  __builtin_amdgcn_s_barrier()
#define VM5   asm volatile("s_waitcnt vmcnt(5)" ::: "memory")
#define VM0   asm volatile("s_waitcnt vmcnt(0)" ::: "memory")
#define PRI1  __builtin_amdgcn_s_setprio(1)
#define PRI0  __builtin_amdgcn_s_setprio(0)

    stage(0, 0);                        // prologue: tile 0 -> buf0 (5 ops)

    #pragma unroll 1
    for (int u = 0; u < NKT; ++u) {
        const int bi = u & 1;
        const unsigned short* ab = lds + (bi ? 8192 : 0);
        const unsigned short* bb = lds + 16384 + (bi ? 12288 : 0);
        if (u < NKT - 1) {
            stage(bi ^ 1, u + 1);       // 5 ops -> other buffer
            VM5;                        // tile u's 5 ops landed; u+1 in flight
        } else {
            VM0;
        }
        BARR;                           // buf[u] valid for all waves

        #pragma unroll
        for (int kc = 0; kc < 2; ++kc) {
            bf16x8 af[4], bf[3];
            #pragma unroll
            for (int m = 0; m < 4; ++m) {
                const int r = wm * 16 + m * 32 + n16;
                af[m] = *(const bf16x8*)&ab[r * 64 + (((kc * 4 + quad) ^ (r & 7)) * 8)];
            }
            #pragma unroll
            for (int n = 0; n < 3; ++n) {
                const int r = wn * 16 + n * 64 + n16;
                bf[n] = *(const bf16x8*)&bb[r * 64 + (((kc * 4 + quad) ^ (r & 7)) * 8)];
            }
            PRI1;
            #pragma unroll
            for (int m = 0; m < 4; ++m)
                #pragma unroll
                for (int n = 0; n < 3; ++n)
                    acc[m][n] = __builtin_amdgcn_mfma_f32_16x16x32_bf16(
                        af[m], bf[n], acc[m][n], 0, 0, 0);
            PRI0;
        }
        BARR;                           // close reads before next overwrite
    }

#undef VM5
#undef VM0

    // ---- epilogue: col-tiles 0-3 = Q (scaled), 4-7 = K, 8-11 = V -> vt ----
    if (bx >= 8) {
        #pragma unroll
        for (int m = 0; m < 4; ++m) {
            const int tt = bm + wm * 16 + m * 32 + quad * 4;
            const size_t bb2 = (size_t)(tt >> 10) * 768;
            const int tin = tt & 1023;
            #pragma unroll
            for (int n = 0; n < 3; ++n) {
                const int col = bn + wn * 16 + n * 64 + n16;
                const int ch = col - 1536;
                const float bv = bias[col];
                ushort4 o4;
                o4.x = f2bf(acc[m][n][0] + bv);
                o4.y = f2bf(acc[m][n][1] + bv);
                o4.z = f2bf(acc[m][n][2] + bv);
                o4.w = f2bf(acc[m][n][3] + bv);
                *(ushort4*)&vt[(bb2 + ch) * 1024 + tin] = o4;
            }
        }
    } else {
        const bool scale_q = bx < 4;
        #pragma unroll
        for (int m = 0; m < 4; ++m) {
            #pragma unroll
            for (int r = 0; r < 4; ++r) {
                const size_t rowoff = (size_t)(bm + wm * 16 + m * 32 + quad * 4 + r) * N;
                #pragma unroll
                for (int n = 0; n < 3; ++n) {
                    const int col = bn + wn * 16 + n * 64 + n16;
                    float v = acc[m][n][r] + bias[col];
                    if (scale_q) v *= SCALE;
                    C[rowoff + col] = f2bf(v);
                }
            }
        }
    }
}

// ---------------- proj GEMM: 64x192 tile, 512 blocks = 2/CU x 256 CUs ----------------
// A = att_bf [8192,768] bf16; Wt = wpt [768,768]; C = out fp32 + bias.
// 256 threads = 4 waves (2x2): per-wave rows wm*16 + m*32 (m=0..1),
// cols wn*16 + n*32 (n=0..5). acc[2][6] = 48 regs.
// LDS: [A0 4096][A1 4096][B0 12288][B1 12288] ushorts = 64 KB -> 2 blocks/CU.
// Per K-tile: stage 8 ops (A 2 + B 6) of t+1 -> other buf; vmcnt(8); barrier;
// 16 ds_read_b128; 24 MFMA; barrier.
__global__ __launch_bounds__(256, 2) void gemm_proj_64x192(
    const unsigned short* __restrict__ A,
    const unsigned short* __restrict__ Wt,
    const float* __restrict__ bias,
    float* __restrict__ C)
{
    constexpr int K = 768;
    constexpr int NKT = 12;

    extern __shared__ unsigned short lds[];

    const int tid  = threadIdx.x;
    const int lane = tid & 63;
    const int w    = tid >> 6;          // 0..3
    const int wm   = w >> 1;            // 0..1
    const int wn   = w & 1;             // 0..1
    const int n16  = lane & 15;
    const int quad = lane >> 4;

    // 512 blocks: xcd = lin&7; s = lin>>3 (0..63); by = xcd*16 + s/4 (0..127);
    // bx = s%4. Batch b's 1024 rows (16 by-tiles) stay on XCD b.
    const int lin = blockIdx.x;
    const int s   = lin >> 3;
    const int by  = (lin & 7) * 16 + (s >> 2);
    const int bx  = s & 3;
    const int bm = by * 64, bn = bx * 192;

    const unsigned short* Asrc = A  + (size_t)bm * K;
    const unsigned short* Bsrc = Wt + (size_t)bn * K;

    auto stage = [&](int bi, int kt) {
        unsigned short* ab = lds + (bi ? 4096 : 0);
        unsigned short* bb = lds + 8192 + (bi ? 12288 : 0);
        #pragma unroll
        for (int i = 0; i < 2; ++i) {
            const int li = i * 256 + tid;        // 0..511
            const int row = li >> 3;             // 0..63
            const int sl  = li & 7;
            async_copy16(&ab[li * 8],
                         Asrc + (size_t)row * K + ((sl ^ (row & 7)) * 8) + kt * 64);
        }
        #pragma unroll
        for (int i = 0; i < 6; ++i) {
            const int li = i * 256 + tid;        // 0..1535
            const int row = li >> 3;             // 0..191
            const int sl  = li & 7;
            async_copy16(&bb[li * 8],
                         Bsrc + (size_t)row * K + ((sl ^ (row & 7)) * 8) + kt * 64);
        }
    };

    f32x4 acc[2][6] = {};

#define BARR  __builtin_amdgcn_s_barrier()
#define VM8   asm volatile("s_waitcnt vmcnt(8)" ::: "memory")
#define VM0   asm volatile("s_waitcnt vmcnt(0)" ::: "memory")
#define PRI1  __builtin_amdgcn_s_setprio(1)
#define PRI0  __builtin_amdgcn_s_setprio(0)

    stage(0, 0);

    #pragma unroll 1
    for (int u = 0; u < NKT; ++u) {
        const int bi = u & 1;
        const unsigned short* ab = lds + (bi ? 4096 : 0);
        const unsigned short* bb = lds + 8192 + (bi ? 12288 : 0);
        if (u < NKT - 1) {
            stage(bi ^ 1, u + 1);       // 8 ops -> other buffer
            VM8;                        // tile u's 8 landed; u+1's 8 in flight
        } else {
            VM0;
        }
        BARR;

        #pragma unroll
        for (int kc = 0; kc < 2; ++kc) {
            bf16x8 af[2], bf[6];
            #pragma unroll
            for (int m = 0; m < 2; ++m) {
                const int r = wm * 16 + m * 32 + n16;
                af[m] = *(const bf16x8*)&ab[r * 64 + (((kc * 4 + quad) ^ (r & 7)) * 8)];
            }
            #pragma unroll
            for (int n = 0; n < 6; ++n) {
                const int r = wn * 16 + n * 32 + n16;
                bf[n] = *(const bf16x8*)&bb[r * 64 + (((kc * 4 + quad) ^ (r & 7)) * 8)];
            }
            PRI1;
            #pragma unroll
            for (int m = 0; m < 2; ++m)
                #pragma unroll
                for (int n = 0; n < 6; ++n)
                    acc[m][n] = __builtin_amdgcn_mfma_f32_16x16x32_bf16(
                        af[m], bf[n], acc[m][n], 0, 0, 0);
            PRI0;
        }
        BARR;
    }

#undef VM8
#undef VM0

    // ---- epilogue: fp32 + bias ----
    #pragma unroll
    for (int m = 0; m < 2; ++m) {
        #pragma unroll
        for (int r = 0; r < 4; ++r) {
            const size_t rowoff = (size_t)(bm + wm * 16 + m * 32 + quad * 4 + r) * E_;
            #pragma unroll
            for (int n = 0; n < 6; ++n) {
                const int col = bn + wn * 16 + n * 32 + n16;
                C[rowoff + col] = acc[m][n][r] + bias[col];
            }
        }
    }
}

// ---------------- Flash attention v7 (unchanged): pipelined LDS staging, no Ps ----------------
#define BKEY 128

__global__ __launch_bounds__(256, 3) void flash_attn_kernel(
    const unsigned short* __restrict__ qkv,
    const unsigned short* __restrict__ vt,   // [(b*H+h)*64+d][1024] bf16
    unsigned short* __restrict__ out)
{
    __shared__ __align__(16) unsigned short Ks[2][BKEY * 64];   // double-buffered K
    __shared__ __align__(16) unsigned short Vts[64 * BKEY];     // single-buffered V^T

    const int tid = threadIdx.x;
    const int idx = blockIdx.x;
    const int xcd = idx & 7;
    const int j   = idx >> 3;           // 0..95
    const int head = xcd * 12 + (j % 12);
    const int p    = j / 12;            // 0..7
    const int h = head % H_;
    const int b = head / H_;

    const int lane = tid & 63;
    const int w    = tid >> 6;
    const int n16  = lane & 15;
    const int quad = lane >> 4;

    const size_t base = (size_t)b * T_ * E3;
    const unsigned short* qbase = qkv + base + h * D_;          // pre-scaled q
    const unsigned short* kbase = qkv + base + E_ + h * D_;
    const unsigned short* vtb   = vt + (size_t)(b * H_ + h) * 64 * 1024;

    const int lrow = lane >> 3;
    const int lcol = ((lane & 7) ^ lrow) * 8;
    const int vr4 = lane >> 4;
    const int vc  = lane & 15;

    const int qtA = p, qtB = 15 - p;
    const int nIterA = (qtA + 2) >> 1;
    const int nIterB = (qtB + 2) >> 1;
    const int wqA = qtA * 64 + w * 16;
    const int wqB = qtB * 64 + w * 16;

    const unsigned short* qrpA = qbase + (size_t)(wqA + n16) * E3 + quad * 8;
    bf16x8 qfA0 = *(const bf16x8*)qrpA;
    bf16x8 qfA1 = *(const bf16x8*)(qrpA + 32);
    const unsigned short* qrpB = qbase + (size_t)(wqB + n16) * E3 + quad * 8;
    bf16x8 qfB0 = *(const bf16x8*)qrpB;
    bf16x8 qfB1 = *(const bf16x8*)(qrpB + 32);

    f32x4 oA[4] = {}, oB[4] = {};
    float lsA = 0.f, lsB = 0.f;

    const int sLo = n16 + 32 * (quad & 1);
    const int sHi = sLo + 16;
    const bool hiSel = quad >= 2;

    auto stageK = [&](int t) {                 // K tile t -> Ks[t&1] (4 loads)
        unsigned short* dst = Ks[t & 1];
        const int k0 = t * BKEY;
        #pragma unroll
        for (int i = 0; i < 4; ++i) {
            const int c = w * 4 + i;
            const int row = c * 8 + lrow;
            async_copy16(&dst[c * 512], kbase + (size_t)(k0 + row) * E3 + lcol);
        }
    };
    auto stageV = [&](int t) {                 // V tile t -> Vts (4 loads)
        const int k0 = t * BKEY;
        #pragma unroll
        for (int i = 0; i < 4; ++i) {
            const int jj = w * 4 + i;
            const int row = 4 * jj + vr4;
            async_copy16(&Vts[4 * jj * BKEY],
                         vtb + (size_t)row * 1024 + k0 + ((vc ^ (row & 15)) * 8));
        }
    };

    auto phase = [&](bf16x8 qf0, bf16x8 qf1, f32x4* o, float& lsum,
                     int wave_q_min, int k0, const unsigned short* Kb,
                     bool doMid, bool notLast) {
        int knt_lim = ((wave_q_min + 15 - k0) >> 4) + 1;
        if (knt_lim > 8) knt_lim = 8;
        const int ks_lim = (knt_lim + 1) >> 1;
        const int nkp = ks_lim * 2;
        int Ab2 = wave_q_min - k0 - 15;
        int kfull = Ab2 < 0 ? 0 : (Ab2 >> 4) + 1;
        if (kfull > 8) kfull = 8;

        const int qcol = wave_q_min + n16;           // this lane's q row

        f32x4 s[8];
        #pragma unroll
        for (int knt = 0; knt < 8; ++knt) {
            if (knt < knt_lim) {
                const int r = knt * 16 + n16;
                bf16x8 kf0 = *(const bf16x8*)&Kb[r * 64 + ((0 + quad) ^ (r & 7)) * 8];
                bf16x8 kf1 = *(const bf16x8*)&Kb[r * 64 + ((4 + quad) ^ (r & 7)) * 8];
                f32x4 acc = {0.f, 0.f, 0.f, 0.f};
                acc = __builtin_amdgcn_mfma_f32_16x16x32_bf16(kf0, qf0, acc, 0, 0, 0);
                acc = __builtin_amdgcn_mfma_f32_16x16x32_bf16(kf1, qf1, acc, 0, 0, 0);
                s[knt] = acc;
            }
        }
        #pragma unroll
        for (int knt = 0; knt < 8; ++knt) {
            if (knt >= kfull && knt < nkp) {
                const int krow = k0 + knt * 16 + quad * 4;
                #pragma unroll
                for (int r = 0; r < 4; ++r) {
                    float v = (knt < knt_lim) ? s[knt][r] : -1e30f;
                    if (krow + r > qcol) v = -1e30f;
                    s[knt][r] = v;
                }
            }
        }

        unsigned int e0[8], e1[8];
        #pragma unroll
        for (int knt = 0; knt < 8; ++knt) {
            if (knt < nkp) {
                float pv0 = __builtin_amdgcn_exp2f(s[knt][0]);
                float pv1 = __builtin_amdgcn_exp2f(s[knt][1]);
                float pv2 = __builtin_amdgcn_exp2f(s[knt][2]);
                float pv3 = __builtin_amdgcn_exp2f(s[knt][3]);
                lsum += (pv0 + pv1) + (pv2 + pv3);
                unsigned int u0 = __builtin_bit_cast(unsigned int, pv0);
                unsigned int u1 = __builtin_bit_cast(unsigned int, pv1);
                unsigned int u2 = __builtin_bit_cast(unsigned int, pv2);
                unsigned int u3 = __builtin_bit_cast(unsigned int, pv3);
                e0[knt] = ((u0 + 0x8000u) >> 16) | ((u1 + 0x8000u) & 0xffff0000u);
                e1[knt] = ((u2 + 0x8000u) >> 16) | ((u3 + 0x8000u) & 0xffff0000u);
            }
        }

        if (doMid) {
            if (notLast) asm volatile("s_waitcnt vmcnt(4)" ::: "memory");
            else         asm volatile("s_waitcnt vmcnt(0)" ::: "memory");
            __builtin_amdgcn_s_barrier();
        }

        #pragma unroll
        for (int ks = 0; ks < 4; ++ks) {
            if (ks < ks_lim) {
                const int kA = 2 * ks, kB = 2 * ks + 1;
                unsigned int a0 = (unsigned)__shfl((int)e0[kA], sLo);
                unsigned int a1 = (unsigned)__shfl((int)e1[kA], sLo);
                unsigned int a2 = (unsigned)__shfl((int)e0[kA], sHi);
                unsigned int a3 = (unsigned)__shfl((int)e1[kA], sHi);
                unsigned int b0 = (unsigned)__shfl((int)e0[kB], sLo);
                unsigned int b1 = (unsigned)__shfl((int)e1[kB], sLo);
                unsigned int b2 = (unsigned)__shfl((int)e0[kB], sHi);
                unsigned int b3 = (unsigned)__shfl((int)e1[kB], sHi);
                uint4 pu;
                pu.x = hiSel ? b0 : a0;
                pu.y = hiSel ? b1 : a1;
                pu.z = hiSel ? b2 : a2;
                pu.w = hiSel ? b3 : a3;
                bf16x8 pf = __builtin_bit_cast(bf16x8, pu);
                #pragma unroll
                for (int dt = 0; dt < 4; ++dt) {
                    const int row = dt * 16 + n16;
                    bf16x8 vf = *(const bf16x8*)&Vts[row * BKEY +
                                    (((ks * 4 + quad) ^ n16) * 8)];
                    o[dt] = __builtin_amdgcn_mfma_f32_16x16x32_bf16(pf, vf, o[dt], 0, 0, 0);
                }
            }
        }
    };

    stageK(0);
    asm volatile("s_waitcnt vmcnt(0)" ::: "memory");
    __builtin_amdgcn_s_barrier();

    for (int it = 0; it < nIterB; ++it) {
        const int k0 = it * BKEY;
        const bool notLast = (it + 1 < nIterB);

        stageV(it);
        if (notLast) stageK(it + 1);
        const unsigned short* Kb = Ks[it & 1];

        phase(qfB0, qfB1, oB, lsB, wqB, k0, Kb, true,  notLast);
        if (it < nIterA)
            phase(qfA0, qfA1, oA, lsA, wqA, k0, Kb, false, notLast);

        asm volatile("s_waitcnt vmcnt(0)" ::: "memory");
        __builtin_amdgcn_s_barrier();
    }

    lsA += __shfl_xor(lsA, 16); lsA += __shfl_xor(lsA, 32);
    lsB += __shfl_xor(lsB, 16); lsB += __shfl_xor(lsB, 32);

    #pragma unroll
    for (int r = 0; r < 4; ++r) {
        const float invA = 1.f / __shfl(lsA, quad * 4 + r);
        unsigned short* orowA = out + ((size_t)b * T_ + wqA + quad * 4 + r) * E_ + h * D_;
        #pragma unroll
        for (int dt = 0; dt < 4; ++dt)
            orowA[dt * 16 + n16] = f2bf(oA[dt][r] * invA);
        const float invB = 1.f / __shfl(lsB, quad * 4 + r);
        unsigned short* orowB = out + ((size_t)b * T_ + wqB + quad * 4 + r) * E_ + h * D_;
        #pragma unroll
        for (int dt = 0; dt < 4; ++dt)
            orowB[dt * 16 + n16] = f2bf(oB[dt][r] * invB);
    }
}

extern "C" void kernel_launch(void* const* d_in, const int* in_sizes, int n_in,
                              void* d_out, int out_size, void* d_ws, size_t ws_size,
                              hipStream_t stream)
{
    const float* x      = (const float*)d_in[0];
    const float* w_attn = (const float*)d_in[1];
    const float* b_attn = (const float*)d_in[2];
    const float* w_proj = (const float*)d_in[3];
    const float* b_proj = (const float*)d_in[4];
    float* out = (float*)d_out;

    const int M = B_ * T_;  // 8192

    unsigned short* x_bf   = (unsigned short*)d_ws;           // [M,E]
    unsigned short* wat    = x_bf + (size_t)M * E_;           // [3E,E]
    unsigned short* wpt    = wat + (size_t)E3 * E_;           // [E,E]
    unsigned short* qkv_bf = wpt + (size_t)E_ * E_;           // [M,3E] (V region unused)
    unsigned short* att_bf = qkv_bf + (size_t)M * E3;         // [M,E]
    unsigned short* vt_bf  = att_bf + (size_t)M * E_;         // [B*H*64,1024]

    static bool attr_set = false;
    if (!attr_set) {
        (void)hipFuncSetAttribute((const void*)gemm_qkv_128x192,
                                  hipFuncAttributeMaxDynamicSharedMemorySize, 81920);
        (void)hipFuncSetAttribute((const void*)gemm_proj_64x192,
                                  hipFuncAttributeMaxDynamicSharedMemorySize, 65536);
        attr_set = true;
    }

    prep_kernel<<<NCVT + NTA + NTP, 256, 0, stream>>>(x, x_bf, w_attn, wat, w_proj, wpt);

    gemm_qkv_128x192<<<dim3(768), dim3(512), 81920, stream>>>(
        x_bf, wat, b_attn, qkv_bf, vt_bf);

    flash_attn_kernel<<<B_ * H_ * 8, 256, 0, stream>>>(qkv_bf, vt_bf, att_bf);

    gemm_proj_64x192<<<dim3(512), dim3(256), 65536, stream>>>(
        att_bf, wpt, b_proj, out);
}